// Round 6
// baseline (355.482 us; speedup 1.0000x reference)
//
#include <hip/hip_runtime.h>

#define NIB_SCALE 100.0f
#define NWAVES_TOTAL 8192   // 2048 blocks x 4 waves: exactly the resident capacity

// ---- DPP helpers (VALU pipe). ctrl: 0xB1 quad_perm xor1, 0x4E quad_perm xor2,
// 0x110+N row_shr, 0x120+N row_ror (16-lane rows), 0x140 row_mirror ----
template<int CTRL>
__device__ __forceinline__ float fdpp(float x) {
    return __int_as_float(__builtin_amdgcn_update_dpp(
        0, __float_as_int(x), CTRL, 0xF, 0xF, true));
}
// lane ^ 4 via ds_swizzle BitMode: offset = (xor<<10)|(or<<5)|and = 0x101F
__device__ __forceinline__ float fswz_xor4(float x) {
    return __int_as_float(__builtin_amdgcn_ds_swizzle(__float_as_int(x), 0x101F));
}
__device__ __forceinline__ float fbperm(int byteIdx, float v) {
    return __int_as_float(__builtin_amdgcn_ds_bpermute(byteIdx, __float_as_int(v)));
}

__device__ __forceinline__ float rsum16d(float v) {
    v += fdpp<0x121>(v); v += fdpp<0x122>(v); v += fdpp<0x124>(v); v += fdpp<0x128>(v);
    return v;
}
__device__ __forceinline__ float rmax16d(float v) {
    v = fmaxf(v, fdpp<0x121>(v)); v = fmaxf(v, fdpp<0x122>(v));
    v = fmaxf(v, fdpp<0x124>(v)); v = fmaxf(v, fdpp<0x128>(v));
    return v;
}
// inclusive ascending prefix sum within the 16-lane row
__device__ __forceinline__ float scan16d(float v) {
    v += fdpp<0x111>(v); v += fdpp<0x112>(v); v += fdpp<0x114>(v); v += fdpp<0x118>(v);
    return v;
}
__device__ __forceinline__ float softmax16d(float v) {
    float m = rmax16d(v);
    float e = __expf(NIB_SCALE * (v - m));
    float s = rsum16d(e);
    return e / s;
}
__device__ __forceinline__ float sharp_sigmoid(float c) {
    // softmax2(100*[1-c, c])[1] = 1/(1+exp(100*(1-2c)))
    return 1.0f / (1.0f + __expf(NIB_SCALE * (1.0f - 2.0f * c)));
}

// build G[j][k] = src[(k-j)&15] via independent row_ror:j DPP movs
#define GATHER_ROT(dst, src)            \
    dst[0]  = (src);                    \
    dst[1]  = fdpp<0x121>(src);         \
    dst[2]  = fdpp<0x122>(src);         \
    dst[3]  = fdpp<0x123>(src);         \
    dst[4]  = fdpp<0x124>(src);         \
    dst[5]  = fdpp<0x125>(src);         \
    dst[6]  = fdpp<0x126>(src);         \
    dst[7]  = fdpp<0x127>(src);         \
    dst[8]  = fdpp<0x128>(src);         \
    dst[9]  = fdpp<0x129>(src);         \
    dst[10] = fdpp<0x12A>(src);         \
    dst[11] = fdpp<0x12B>(src);         \
    dst[12] = fdpp<0x12C>(src);         \
    dst[13] = fdpp<0x12D>(src);         \
    dst[14] = fdpp<0x12E>(src);         \
    dst[15] = fdpp<0x12F>(src);

// Persistent-style: each wave owns ROWS/8192 rows; software-pipelined so the
// next row's loads are in flight during the current row's dependent math
// (continuous memory request generation instead of load/compute convoys).
__global__ __launch_bounds__(256, 6) void nalu_kernel(const float* __restrict__ A,
                                                      const float* __restrict__ B,
                                                      float* __restrict__ O,
                                                      int nrows) {
    // per-group scratch; groups never span waves -> wave-synchronous, no barriers
    __shared__ __align__(16) float sQL[16][16];
    __shared__ __align__(16) float sQH[16][16];
    __shared__ __align__(16) float sPSL[16][16];
    __shared__ __align__(16) float sPSH[16][16];
    __shared__ __align__(16) float sOV[4][4][4];  // [wave][{o16l,o15l,o16h,o15h}][byte]

    const int tid = threadIdx.x;
    const int k = tid & 15;           // lane within the 16-lane group
    const int g = tid >> 4;           // group id within block (16 groups)
    const int b = g & 3;              // byte index handled by this group
    const int w = tid >> 6;           // wave id within block
    const int lane64 = tid & 63;
    // bpermute source lane: s = ((k&3)<<2)|(k>>2) within the 16-lane group
    const int bpermIdx = 4 * ((lane64 & 48) | ((k & 3) << 2) | (k >> 2));
    const int wg = blockIdx.x * 4 + w; // global wave id in [0, NWAVES_TOTAL)
    const int RP = (nrows + NWAVES_TOTAL - 1) / NWAVES_TOTAL;

    int row = wg;
    float4 cA0, cA1, cA2, cA3, cB0, cB1, cB2, cB3;
    if (row < nrows) {
        const float4* pa4 = (const float4*)(A + (long)row * 1024 + b * 256);
        const float4* pb4 = (const float4*)(B + (long)row * 1024 + b * 256);
        cA0 = pa4[k]; cA1 = pa4[16 + k]; cA2 = pa4[32 + k]; cA3 = pa4[48 + k];
        cB0 = pb4[k]; cB1 = pb4[16 + k]; cB2 = pb4[32 + k]; cB3 = pb4[48 + k];
    }

    for (int it = 0; it < RP; ++it) {
        const int nxtRow = row + NWAVES_TOTAL;

        // ---- logits from current regs (frees cA*/cB* early) ----
        // rows e = 4j + (k>>2): own 4 + quad butterflies (xor1, xor2)
        float ahj[4], bhj[4];
        {
            float s;
            s = (cA0.x + cA0.y) + (cA0.z + cA0.w); s += fdpp<0xB1>(s); s += fdpp<0x4E>(s); ahj[0] = s;
            s = (cA1.x + cA1.y) + (cA1.z + cA1.w); s += fdpp<0xB1>(s); s += fdpp<0x4E>(s); ahj[1] = s;
            s = (cA2.x + cA2.y) + (cA2.z + cA2.w); s += fdpp<0xB1>(s); s += fdpp<0x4E>(s); ahj[2] = s;
            s = (cA3.x + cA3.y) + (cA3.z + cA3.w); s += fdpp<0xB1>(s); s += fdpp<0x4E>(s); ahj[3] = s;
            s = (cB0.x + cB0.y) + (cB0.z + cB0.w); s += fdpp<0xB1>(s); s += fdpp<0x4E>(s); bhj[0] = s;
            s = (cB1.x + cB1.y) + (cB1.z + cB1.w); s += fdpp<0xB1>(s); s += fdpp<0x4E>(s); bhj[1] = s;
            s = (cB2.x + cB2.y) + (cB2.z + cB2.w); s += fdpp<0xB1>(s); s += fdpp<0x4E>(s); bhj[2] = s;
            s = (cB3.x + cB3.y) + (cB3.z + cB3.w); s += fdpp<0xB1>(s); s += fdpp<0x4E>(s); bhj[3] = s;
        }
        // cols l = 4(k&3)+i: own 4 + xor4 (swizzle) + xor8 (row_ror:8)
        float ali[4], bli[4];
        {
            float s;
            s = (cA0.x + cA1.x) + (cA2.x + cA3.x); s += fswz_xor4(s); s += fdpp<0x128>(s); ali[0] = s;
            s = (cA0.y + cA1.y) + (cA2.y + cA3.y); s += fswz_xor4(s); s += fdpp<0x128>(s); ali[1] = s;
            s = (cA0.z + cA1.z) + (cA2.z + cA3.z); s += fswz_xor4(s); s += fdpp<0x128>(s); ali[2] = s;
            s = (cA0.w + cA1.w) + (cA2.w + cA3.w); s += fswz_xor4(s); s += fdpp<0x128>(s); ali[3] = s;
            s = (cB0.x + cB1.x) + (cB2.x + cB3.x); s += fswz_xor4(s); s += fdpp<0x128>(s); bli[0] = s;
            s = (cB0.y + cB1.y) + (cB2.y + cB3.y); s += fswz_xor4(s); s += fdpp<0x128>(s); bli[1] = s;
            s = (cB0.z + cB1.z) + (cB2.z + cB3.z); s += fswz_xor4(s); s += fdpp<0x128>(s); bli[2] = s;
            s = (cB0.w + cB1.w) + (cB2.w + cB3.w); s += fswz_xor4(s); s += fdpp<0x128>(s); bli[3] = s;
        }
        // redistribute one-per-lane: lane s selects its (s>>2 / s&3) element,
        // lane k pulls from s = ((k&3)<<2)|(k>>2) via ds_bpermute
        float t0, t1;
        t0 = (k & 4) ? ali[1] : ali[0]; t1 = (k & 4) ? ali[3] : ali[2];
        float al = fbperm(bpermIdx, (k & 8) ? t1 : t0);
        t0 = (k & 4) ? bli[1] : bli[0]; t1 = (k & 4) ? bli[3] : bli[2];
        float bl = fbperm(bpermIdx, (k & 8) ? t1 : t0);
        t0 = (k & 1) ? ahj[1] : ahj[0]; t1 = (k & 1) ? ahj[3] : ahj[2];
        float ah = fbperm(bpermIdx, (k & 2) ? t1 : t0);
        t0 = (k & 1) ? bhj[1] : bhj[0]; t1 = (k & 1) ? bhj[3] : bhj[2];
        float bh = fbperm(bpermIdx, (k & 2) ? t1 : t0);

        // ---- PREFETCH next row (current regs are dead now) ----
        const bool vn = (it + 1 < RP) && (nxtRow < nrows);
        if (vn) {
            const float4* pa4 = (const float4*)(A + (long)nxtRow * 1024 + b * 256);
            const float4* pb4 = (const float4*)(B + (long)nxtRow * 1024 + b * 256);
            cA0 = pa4[k]; cA1 = pa4[16 + k]; cA2 = pa4[32 + k]; cA3 = pa4[48 + k];
            cB0 = pb4[k]; cB1 = pb4[16 + k]; cB2 = pb4[32 + k]; cB3 = pb4[48 + k];
        }

        // ---- factorized sharp softmaxes (exact vs the joint 512-softmax) ----
        float pal = softmax16d(al);
        float pbl = softmax16d(bl);
        float pah = softmax16d(ah);
        float pbh = softmax16d(bh);

        sQL[g][k] = pbl;
        sQH[g][k] = pbh;

        // overflow masses, pure DPP:
        // mir[k]=q[15-k]; T15[k]=sum_{v>=15-k} q[v]; ov15=sum_{a+v>=15} p[a]q[v]
        float mirl = fdpp<0x140>(pbl);
        float mirh = fdpp<0x140>(pbh);
        float T15l = scan16d(mirl);
        float T15h = scan16d(mirh);
        float ov15l = rsum16d(pal * T15l);
        float c15l  = rsum16d(pal * mirl);
        float ov15h = rsum16d(pah * T15h);
        float c15h  = rsum16d(pah * mirh);
        float ov16l = ov15l - c15l;
        float ov16h = ov15h - c15h;

        // publish per-byte carry constants (uniform within group)
        sOV[w][0][b] = ov16l;
        sOV[w][1][b] = ov15l;
        sOV[w][2][b] = ov16h;
        sOV[w][3][b] = ov15h;

        // ---- circular convolutions r[k] = sum_j p[(k-j)&15] q[j] ----
        float QL[16], QH[16];
        *(float4*)&QL[0]  = *(const float4*)&sQL[g][0];
        *(float4*)&QL[4]  = *(const float4*)&sQL[g][4];
        *(float4*)&QL[8]  = *(const float4*)&sQL[g][8];
        *(float4*)&QL[12] = *(const float4*)&sQL[g][12];
        float GL[16];
        GATHER_ROT(GL, pal)
        float rl = 0.f;
        #pragma unroll
        for (int j = 0; j < 16; ++j) rl = fmaf(GL[j], QL[j], rl);

        *(float4*)&QH[0]  = *(const float4*)&sQH[g][0];
        *(float4*)&QH[4]  = *(const float4*)&sQH[g][4];
        *(float4*)&QH[8]  = *(const float4*)&sQH[g][8];
        *(float4*)&QH[12] = *(const float4*)&sQH[g][12];
        float GH[16];
        GATHER_ROT(GH, pah)
        float rh = 0.f;
        #pragma unroll
        for (int j = 0; j < 16; ++j) rh = fmaf(GH[j], QH[j], rh);

        // ---- serial carry chain (tiny; redundantly computed by every lane) ----
        float4 O16L = *(const float4*)&sOV[w][0][0];
        float4 O15L = *(const float4*)&sOV[w][1][0];
        float4 O16H = *(const float4*)&sOV[w][2][0];
        float4 O15H = *(const float4*)&sOV[w][3][0];

        float qc1_0 = sharp_sigmoid(O16L.x);
        float qc0_0 = 1.f - qc1_0;
        float pc1_1 = sharp_sigmoid(qc0_0 * O16H.x + qc1_0 * O15H.x);
        float pc0_1 = 1.f - pc1_1;
        float qc1_1 = sharp_sigmoid(pc0_1 * O16L.y + pc1_1 * O15L.y);
        float qc0_1 = 1.f - qc1_1;
        float pc1_2 = sharp_sigmoid(qc0_1 * O16H.y + qc1_1 * O15H.y);
        float pc0_2 = 1.f - pc1_2;
        float qc1_2 = sharp_sigmoid(pc0_2 * O16L.z + pc1_2 * O15L.z);
        float qc0_2 = 1.f - qc1_2;
        float pc1_3 = sharp_sigmoid(qc0_2 * O16H.z + qc1_2 * O15H.z);
        float pc0_3 = 1.f - pc1_3;
        float qc1_3 = sharp_sigmoid(pc0_3 * O16L.w + pc1_3 * O15L.w);
        float qc0_3 = 1.f - qc1_3;

        float pc0 = b == 0 ? 1.f   : b == 1 ? pc0_1 : b == 2 ? pc0_2 : pc0_3;
        float pc1 = b == 0 ? 0.f   : b == 1 ? pc1_1 : b == 2 ? pc1_2 : pc1_3;
        float qc0 = b == 0 ? qc0_0 : b == 1 ? qc0_1 : b == 2 ? qc0_2 : qc0_3;
        float qc1 = b == 0 ? qc1_0 : b == 1 ? qc1_1 : b == 2 ? qc1_2 : qc1_3;

        // ---- nibble sums with carry mixing ----
        float slow  = pc0 * rl + pc1 * fdpp<0x121>(rl);   // rl[(k-1)&15]
        float shigh = qc0 * rh + qc1 * fdpp<0x121>(rh);

        // ---- n2b: out[16h + l] = psh[h] * psl[l] ----
        float psl = softmax16d(slow);
        float psh = softmax16d(shigh);
        sPSL[g][k] = psl;
        sPSH[g][k] = psh;

        float4 pslq = *(const float4*)&sPSL[g][4 * (k & 3)];
        if (row < nrows) {
            float* po = O + (long)row * 1024 + b * 256;
            #pragma unroll
            for (int c = 0; c < 4; ++c) {
                float hs = sPSH[g][4 * c + (k >> 2)];
                float4 o4 = make_float4(hs * pslq.x, hs * pslq.y, hs * pslq.z, hs * pslq.w);
                *(float4*)(po + 64 * c + 4 * k) = o4;
            }
        }
        row = nxtRow;
    }
}

extern "C" void kernel_launch(void* const* d_in, const int* in_sizes, int n_in,
                              void* d_out, int out_size, void* d_ws, size_t ws_size,
                              hipStream_t stream) {
    const float* A = (const float*)d_in[0];
    const float* B = (const float*)d_in[1];
    float* O = (float*)d_out;
    int nrows = in_sizes[0] / 1024;          // [B,4,256] -> B
    nalu_kernel<<<NWAVES_TOTAL / 4, 256, 0, stream>>>(A, B, O, nrows);
}

// Round 7
// 310.778 us; speedup vs baseline: 1.1438x; 1.1438x over previous
//
#include <hip/hip_runtime.h>

#define NIB_SCALE 100.0f

// ---- DPP helpers (VALU pipe). ctrl: 0xB1 quad_perm xor1, 0x4E quad_perm xor2,
// 0x110+N row_shr, 0x120+N row_ror (16-lane rows), 0x140 row_mirror ----
template<int CTRL>
__device__ __forceinline__ float fdpp(float x) {
    return __int_as_float(__builtin_amdgcn_update_dpp(
        0, __float_as_int(x), CTRL, 0xF, 0xF, true));
}
// lane ^ 4 via ds_swizzle BitMode: offset = (xor<<10)|(or<<5)|and = 0x101F
__device__ __forceinline__ float fswz_xor4(float x) {
    return __int_as_float(__builtin_amdgcn_ds_swizzle(__float_as_int(x), 0x101F));
}
__device__ __forceinline__ float fbperm(int byteIdx, float v) {
    return __int_as_float(__builtin_amdgcn_ds_bpermute(byteIdx, __float_as_int(v)));
}

__device__ __forceinline__ float rsum16d(float v) {
    v += fdpp<0x121>(v); v += fdpp<0x122>(v); v += fdpp<0x124>(v); v += fdpp<0x128>(v);
    return v;
}
__device__ __forceinline__ float rmax16d(float v) {
    v = fmaxf(v, fdpp<0x121>(v)); v = fmaxf(v, fdpp<0x122>(v));
    v = fmaxf(v, fdpp<0x124>(v)); v = fmaxf(v, fdpp<0x128>(v));
    return v;
}
// inclusive ascending prefix sum within the 16-lane row
__device__ __forceinline__ float scan16d(float v) {
    v += fdpp<0x111>(v); v += fdpp<0x112>(v); v += fdpp<0x114>(v); v += fdpp<0x118>(v);
    return v;
}
__device__ __forceinline__ float softmax16d(float v) {
    float m = rmax16d(v);
    float e = __expf(NIB_SCALE * (v - m));
    float s = rsum16d(e);
    return e / s;
}
__device__ __forceinline__ float sharp_sigmoid(float c) {
    // softmax2(100*[1-c, c])[1] = 1/(1+exp(100*(1-2c)))
    return 1.0f / (1.0f + __expf(NIB_SCALE * (1.0f - 2.0f * c)));
}

// build G[j][k] = src[(k-j)&15] via independent row_ror:j DPP movs
#define GATHER_ROT(dst, src)            \
    dst[0]  = (src);                    \
    dst[1]  = fdpp<0x121>(src);         \
    dst[2]  = fdpp<0x122>(src);         \
    dst[3]  = fdpp<0x123>(src);         \
    dst[4]  = fdpp<0x124>(src);         \
    dst[5]  = fdpp<0x125>(src);         \
    dst[6]  = fdpp<0x126>(src);         \
    dst[7]  = fdpp<0x127>(src);         \
    dst[8]  = fdpp<0x128>(src);         \
    dst[9]  = fdpp<0x129>(src);         \
    dst[10] = fdpp<0x12A>(src);         \
    dst[11] = fdpp<0x12B>(src);         \
    dst[12] = fdpp<0x12C>(src);         \
    dst[13] = fdpp<0x12D>(src);         \
    dst[14] = fdpp<0x12E>(src);         \
    dst[15] = fdpp<0x12F>(src);

struct SharedBufs {
    float sQL[16][16];
    float sQH[16][16];
    float sPSL[16][16];
    float sPSH[16][16];
    float sOV[4][4][4];   // [wave][{o16l,o15l,o16h,o15h}][byte]
};

// Full per-row pipeline from the 8 in-register float4s (R6-verified math).
__device__ __forceinline__ void process_row(
        const float4 cA[4], const float4 cB[4], float* __restrict__ O,
        long rowbase, bool valid, SharedBufs& S,
        int k, int g, int b, int w, int bpermIdx) {
    // ---- logits ----
    // rows e = 4j + (k>>2): own 4 + quad butterflies (xor1, xor2)
    float ahj[4], bhj[4], ali[4], bli[4];
    #pragma unroll
    for (int j = 0; j < 4; ++j) {
        float s = (cA[j].x + cA[j].y) + (cA[j].z + cA[j].w);
        s += fdpp<0xB1>(s); s += fdpp<0x4E>(s); ahj[j] = s;
        float t = (cB[j].x + cB[j].y) + (cB[j].z + cB[j].w);
        t += fdpp<0xB1>(t); t += fdpp<0x4E>(t); bhj[j] = t;
    }
    // cols l = 4(k&3)+i: own 4 + xor4 (swizzle) + xor8 (row_ror:8)
    {
        float s;
        s = (cA[0].x + cA[1].x) + (cA[2].x + cA[3].x); s += fswz_xor4(s); s += fdpp<0x128>(s); ali[0] = s;
        s = (cA[0].y + cA[1].y) + (cA[2].y + cA[3].y); s += fswz_xor4(s); s += fdpp<0x128>(s); ali[1] = s;
        s = (cA[0].z + cA[1].z) + (cA[2].z + cA[3].z); s += fswz_xor4(s); s += fdpp<0x128>(s); ali[2] = s;
        s = (cA[0].w + cA[1].w) + (cA[2].w + cA[3].w); s += fswz_xor4(s); s += fdpp<0x128>(s); ali[3] = s;
        s = (cB[0].x + cB[1].x) + (cB[2].x + cB[3].x); s += fswz_xor4(s); s += fdpp<0x128>(s); bli[0] = s;
        s = (cB[0].y + cB[1].y) + (cB[2].y + cB[3].y); s += fswz_xor4(s); s += fdpp<0x128>(s); bli[1] = s;
        s = (cB[0].z + cB[1].z) + (cB[2].z + cB[3].z); s += fswz_xor4(s); s += fdpp<0x128>(s); bli[2] = s;
        s = (cB[0].w + cB[1].w) + (cB[2].w + cB[3].w); s += fswz_xor4(s); s += fdpp<0x128>(s); bli[3] = s;
    }
    // redistribute one-per-lane: lane k pulls from s = ((k&3)<<2)|(k>>2)
    float t0, t1;
    t0 = (k & 4) ? ali[1] : ali[0]; t1 = (k & 4) ? ali[3] : ali[2];
    float al = fbperm(bpermIdx, (k & 8) ? t1 : t0);
    t0 = (k & 4) ? bli[1] : bli[0]; t1 = (k & 4) ? bli[3] : bli[2];
    float bl = fbperm(bpermIdx, (k & 8) ? t1 : t0);
    t0 = (k & 1) ? ahj[1] : ahj[0]; t1 = (k & 1) ? ahj[3] : ahj[2];
    float ah = fbperm(bpermIdx, (k & 2) ? t1 : t0);
    t0 = (k & 1) ? bhj[1] : bhj[0]; t1 = (k & 1) ? bhj[3] : bhj[2];
    float bh = fbperm(bpermIdx, (k & 2) ? t1 : t0);

    // ---- factorized sharp softmaxes (exact vs the joint 512-softmax) ----
    float pal = softmax16d(al);
    float pbl = softmax16d(bl);
    float pah = softmax16d(ah);
    float pbh = softmax16d(bh);

    S.sQL[g][k] = pbl;
    S.sQH[g][k] = pbh;

    // overflow masses, pure DPP
    float mirl = fdpp<0x140>(pbl);
    float mirh = fdpp<0x140>(pbh);
    float T15l = scan16d(mirl);
    float T15h = scan16d(mirh);
    float ov15l = rsum16d(pal * T15l);
    float c15l  = rsum16d(pal * mirl);
    float ov15h = rsum16d(pah * T15h);
    float c15h  = rsum16d(pah * mirh);
    float ov16l = ov15l - c15l;
    float ov16h = ov15h - c15h;

    S.sOV[w][0][b] = ov16l;
    S.sOV[w][1][b] = ov15l;
    S.sOV[w][2][b] = ov16h;
    S.sOV[w][3][b] = ov15h;

    // ---- circular convolutions r[k] = sum_j p[(k-j)&15] q[j] ----
    float QL[16], QH[16];
    *(float4*)&QL[0]  = *(const float4*)&S.sQL[g][0];
    *(float4*)&QL[4]  = *(const float4*)&S.sQL[g][4];
    *(float4*)&QL[8]  = *(const float4*)&S.sQL[g][8];
    *(float4*)&QL[12] = *(const float4*)&S.sQL[g][12];
    float GL[16];
    GATHER_ROT(GL, pal)
    float rl = 0.f;
    #pragma unroll
    for (int j = 0; j < 16; ++j) rl = fmaf(GL[j], QL[j], rl);

    *(float4*)&QH[0]  = *(const float4*)&S.sQH[g][0];
    *(float4*)&QH[4]  = *(const float4*)&S.sQH[g][4];
    *(float4*)&QH[8]  = *(const float4*)&S.sQH[g][8];
    *(float4*)&QH[12] = *(const float4*)&S.sQH[g][12];
    float GH[16];
    GATHER_ROT(GH, pah)
    float rh = 0.f;
    #pragma unroll
    for (int j = 0; j < 16; ++j) rh = fmaf(GH[j], QH[j], rh);

    // ---- serial carry chain (tiny; redundantly computed by every lane) ----
    float4 O16L = *(const float4*)&S.sOV[w][0][0];
    float4 O15L = *(const float4*)&S.sOV[w][1][0];
    float4 O16H = *(const float4*)&S.sOV[w][2][0];
    float4 O15H = *(const float4*)&S.sOV[w][3][0];

    float qc1_0 = sharp_sigmoid(O16L.x);
    float qc0_0 = 1.f - qc1_0;
    float pc1_1 = sharp_sigmoid(qc0_0 * O16H.x + qc1_0 * O15H.x);
    float pc0_1 = 1.f - pc1_1;
    float qc1_1 = sharp_sigmoid(pc0_1 * O16L.y + pc1_1 * O15L.y);
    float qc0_1 = 1.f - qc1_1;
    float pc1_2 = sharp_sigmoid(qc0_1 * O16H.y + qc1_1 * O15H.y);
    float pc0_2 = 1.f - pc1_2;
    float qc1_2 = sharp_sigmoid(pc0_2 * O16L.z + pc1_2 * O15L.z);
    float qc0_2 = 1.f - qc1_2;
    float pc1_3 = sharp_sigmoid(qc0_2 * O16H.z + qc1_2 * O15H.z);
    float pc0_3 = 1.f - pc1_3;
    float qc1_3 = sharp_sigmoid(pc0_3 * O16L.w + pc1_3 * O15L.w);
    float qc0_3 = 1.f - qc1_3;

    float pc0 = b == 0 ? 1.f   : b == 1 ? pc0_1 : b == 2 ? pc0_2 : pc0_3;
    float pc1 = b == 0 ? 0.f   : b == 1 ? pc1_1 : b == 2 ? pc1_2 : pc1_3;
    float qc0 = b == 0 ? qc0_0 : b == 1 ? qc0_1 : b == 2 ? qc0_2 : qc0_3;
    float qc1 = b == 0 ? qc1_0 : b == 1 ? qc1_1 : b == 2 ? qc1_2 : qc1_3;

    // ---- nibble sums with carry mixing ----
    float slow  = pc0 * rl + pc1 * fdpp<0x121>(rl);   // rl[(k-1)&15]
    float shigh = qc0 * rh + qc1 * fdpp<0x121>(rh);

    // ---- n2b: out[16h + l] = psh[h] * psl[l] ----
    float psl = softmax16d(slow);
    float psh = softmax16d(shigh);
    S.sPSL[g][k] = psl;
    S.sPSH[g][k] = psh;

    float4 pslq = *(const float4*)&S.sPSL[g][4 * (k & 3)];
    if (valid) {
        float* po = O + rowbase;
        #pragma unroll
        for (int c = 0; c < 4; ++c) {
            float hs = S.sPSH[g][4 * c + (k >> 2)];
            float4 o4 = make_float4(hs * pslq.x, hs * pslq.y, hs * pslq.z, hs * pslq.w);
            *(float4*)(po + 64 * c + 4 * k) = o4;
        }
    }
}

// One wave = TWO consecutive-chunk rows, straight-line software pipeline:
// all 16 load instructions issue up front (pinned by sched_barrier), row1's
// loads stay in flight (vmcnt) behind row0's ~1300-cycle math.
__global__ __launch_bounds__(256, 4) void nalu_kernel(const float* __restrict__ A,
                                                      const float* __restrict__ B,
                                                      float* __restrict__ O,
                                                      int nrows) {
    __shared__ SharedBufs S;

    const int tid = threadIdx.x;
    const int k = tid & 15;           // lane within the 16-lane group
    const int g = tid >> 4;           // group id within block (16 groups)
    const int b = g & 3;              // byte index handled by this group
    const int w = tid >> 6;           // wave id within block
    const int lane64 = tid & 63;
    const int bpermIdx = 4 * ((lane64 & 48) | ((k & 3) << 2) | (k >> 2));

    const int r0 = blockIdx.x * 8 + w;       // rows r0 and r0+4 for this wave
    const int r1 = r0 + 4;
    if (r0 >= nrows) return;
    const bool v1 = (r1 < nrows);
    const long base0 = (long)r0 * 1024 + b * 256;
    const long base1 = (long)r1 * 1024 + b * 256;

    // ---- issue ALL loads (row0 then row1); each lane 16B, group-contiguous ----
    float4 A0[4], B0[4], A1[4], B1[4];
    {
        const float4* pa = (const float4*)(A + base0);
        const float4* pb = (const float4*)(B + base0);
        #pragma unroll
        for (int j = 0; j < 4; ++j) A0[j] = pa[16 * j + k];
        #pragma unroll
        for (int j = 0; j < 4; ++j) B0[j] = pb[16 * j + k];
    }
    if (v1) {
        const float4* pa = (const float4*)(A + base1);
        const float4* pb = (const float4*)(B + base1);
        #pragma unroll
        for (int j = 0; j < 4; ++j) A1[j] = pa[16 * j + k];
        #pragma unroll
        for (int j = 0; j < 4; ++j) B1[j] = pb[16 * j + k];
    }
    __builtin_amdgcn_sched_barrier(0);   // pin: loads may not sink below here

    process_row(A0, B0, O, base0, true, S, k, g, b, w, bpermIdx);
    if (v1) process_row(A1, B1, O, base1, true, S, k, g, b, w, bpermIdx);
}

extern "C" void kernel_launch(void* const* d_in, const int* in_sizes, int n_in,
                              void* d_out, int out_size, void* d_ws, size_t ws_size,
                              hipStream_t stream) {
    const float* A = (const float*)d_in[0];
    const float* B = (const float*)d_in[1];
    float* O = (float*)d_out;
    int nrows = in_sizes[0] / 1024;          // [B,4,256] -> B
    int grid = (nrows + 7) / 8;              // 8 rows per block (4 waves x 2 rows)
    nalu_kernel<<<grid, 256, 0, stream>>>(A, B, O, nrows);
}